// Round 11
// baseline (408.686 us; speedup 1.0000x reference)
//
#include <hip/hip_runtime.h>
#include <math.h>

#define D_MODEL 256
#define NTOK    8192
#define SEQ     512
#define NB      16
#define NH      8
#define DHEAD   32
#define NE      8
#define EHID    1024
#define CSTRIDE 32

typedef __attribute__((ext_vector_type(8))) short short8;
typedef __attribute__((ext_vector_type(4))) float floatx4;
typedef unsigned short ushort_t;

__device__ __forceinline__ ushort_t bf16r(float f) {
    unsigned int u = __float_as_uint(f);
    u += 0x7fffu + ((u >> 16) & 1u);
    return (ushort_t)(u >> 16);
}

#define GLD16(gsrc, ldst) \
    __builtin_amdgcn_global_load_lds( \
        (const __attribute__((address_space(1))) void*)(gsrc), \
        (__attribute__((address_space(3))) void*)(ldst), 16, 0, 0)

// ---------------------------------------------------------------------------
__global__ __launch_bounds__(256) void wconv_all(
    const float* __restrict__ in_proj_w, const float* __restrict__ out_proj_w,
    const float* __restrict__ w1, const float* __restrict__ w2,
    ushort_t* __restrict__ wball)
{
    const int g = blockIdx.x * 256 + threadIdx.x;
    const float* src; ushort_t* dst; int lo;
    if (g < 98304)        { src = in_proj_w;  dst = wball;           lo = g; }
    else if (g < 131072)  { src = out_proj_w; dst = wball + 393216;  lo = g - 98304; }
    else if (g < 1179648) { src = w1;         dst = wball + 524288;  lo = g - 131072; }
    else                  { src = w2;         dst = wball + 4718592; lo = g - 1179648; }
    float4 v = *(const float4*)(src + (size_t)lo * 4);
    ushort_t o[4] = { bf16r(v.x), bf16r(v.y), bf16r(v.z), bf16r(v.w) };
    *(uint2*)(dst + (size_t)lo * 4) = *(uint2*)o;
}

// ---------------------------------------------------------------------------
__global__ __launch_bounds__(256) void embed_kernel(
    const int* __restrict__ x, const float* __restrict__ emb,
    float* __restrict__ h, ushort_t* __restrict__ hb, int* __restrict__ pad)
{
    __shared__ float wred[4];
    const int n = blockIdx.x;
    const int d = threadIdx.x;
    const int wave = d >> 6;
    const int s = n & (SEQ - 1);
    const int tok = x[n];
    float v = emb[tok * D_MODEL + d] * 16.0f;
    const int j = d >> 1;
    const float c = -9.210340371976184f / 256.0f;
    const float div = expf((float)(2 * j) * c);
    const float ang = (float)s * div;
    v += (d & 1) ? cosf(ang) : sinf(ang);
    h[n * D_MODEL + d] = v;
    hb[n * D_MODEL + d] = bf16r(v);
    float sm = v;
    for (int o = 1; o < 64; o <<= 1) sm += __shfl_xor(sm, o);
    if ((d & 63) == 0) wred[wave] = sm;
    __syncthreads();
    if (d == 0) pad[n] = ((wred[0] + wred[1] + wred[2] + wred[3]) == 0.0f) ? 1 : 0;
}

// ---------------------------------------------------------------------------
// 64x64 bf16 MFMA GEMM, GLD16 + XOR swizzle (round-9 verified).
// ---------------------------------------------------------------------------
#define GF_RELU    1
#define GF_OUTBF16 2
#define GF_GATHER  4
#define GF_SCATTER 8

__global__ __launch_bounds__(256) void gemm_gl64(
    const ushort_t* __restrict__ A, const ushort_t* __restrict__ Bw,
    const float* __restrict__ bias, void* __restrict__ Cout,
    int M, int N, int K,
    const int* __restrict__ counts,
    const int* __restrict__ perm, const float* __restrict__ topw,
    int flags)
{
    __shared__ ushort_t As[64 * 64];
    __shared__ ushort_t Bs[64 * 64];
    const int e = blockIdx.z;
    int cnt, off = 0;
    if (counts) {
        cnt = counts[e * CSTRIDE];
        if ((int)blockIdx.y * 64 >= cnt) return;
        for (int i = 0; i < e; i++) off += counts[i * CSTRIDE];
    } else { cnt = M; }
    const ushort_t* Bp = Bw + (size_t)e * N * K;
    const float* bp = bias + (size_t)e * N;
    const int m0 = blockIdx.y * 64, n0 = blockIdx.x * 64;
    const int tid = threadIdx.x;
    const int lane = tid & 63, wave = tid >> 6;
    const int r8 = lane >> 3;
    const int p  = lane & 7;
    const int kswz = ((p ^ r8) << 3);
    const int row0 = wave * 16;
    size_t asrc[2], bsrc[2];
#pragma unroll
    for (int c = 0; c < 2; c++) {
        const int gr = m0 + row0 + c * 8 + r8;
        const int grc = (gr < cnt) ? gr : m0;
        asrc[c] = (flags & GF_GATHER) ? (size_t)perm[off + grc] : (size_t)(off + grc);
        bsrc[c] = (size_t)(n0 + row0 + c * 8 + r8);
    }
    const int quad = lane >> 4, fr = lane & 15;
    const int wm = (wave & 1) * 32, wn = (wave >> 1) * 32;
    floatx4 acc[2][2];
#pragma unroll
    for (int i = 0; i < 2; i++)
#pragma unroll
        for (int jj = 0; jj < 2; jj++) acc[i][jj] = (floatx4){0.f, 0.f, 0.f, 0.f};

    for (int k0 = 0; k0 < K; k0 += 64) {
        __syncthreads();
#pragma unroll
        for (int c = 0; c < 2; c++) {
            GLD16(A + asrc[c] * K + k0 + kswz, &As[(row0 + c * 8) * 64]);
            GLD16(Bp + bsrc[c] * K + k0 + kswz, &Bs[(row0 + c * 8) * 64]);
        }
        __syncthreads();
#pragma unroll
        for (int ks = 0; ks < 2; ks++) {
            const int sw = (((ks * 4 + quad) ^ (fr & 7)) << 3);
            short8 fa0 = *(const short8*)&As[(wm + fr) * 64 + sw];
            short8 fa1 = *(const short8*)&As[(wm + 16 + fr) * 64 + sw];
            short8 fb0 = *(const short8*)&Bs[(wn + fr) * 64 + sw];
            short8 fb1 = *(const short8*)&Bs[(wn + 16 + fr) * 64 + sw];
            acc[0][0] = __builtin_amdgcn_mfma_f32_16x16x32_bf16(fa0, fb0, acc[0][0], 0, 0, 0);
            acc[0][1] = __builtin_amdgcn_mfma_f32_16x16x32_bf16(fa0, fb1, acc[0][1], 0, 0, 0);
            acc[1][0] = __builtin_amdgcn_mfma_f32_16x16x32_bf16(fa1, fb0, acc[1][0], 0, 0, 0);
            acc[1][1] = __builtin_amdgcn_mfma_f32_16x16x32_bf16(fa1, fb1, acc[1][1], 0, 0, 0);
        }
    }
    const int crow0 = quad * 4;
    const int ccol = fr;
#pragma unroll
    for (int m = 0; m < 2; m++) {
#pragma unroll
        for (int n = 0; n < 2; n++) {
            const int gcol = n0 + wn + n * 16 + ccol;
            const float bsv = bp[gcol];
#pragma unroll
            for (int r = 0; r < 4; r++) {
                const int grow = m0 + wm + m * 16 + crow0 + r;
                if (grow >= cnt) continue;
                float v = acc[m][n][r] + bsv;
                if (flags & GF_RELU) v = fmaxf(v, 0.f);
                if (flags & GF_SCATTER) {
                    const int tok = perm[off + grow];
                    ((float*)Cout)[(size_t)tok * N + gcol] = v * topw[tok];
                } else if (flags & GF_OUTBF16) {
                    ((ushort_t*)Cout)[(size_t)(off + grow) * N + gcol] = bf16r(v);
                } else {
                    ((float*)Cout)[(size_t)(off + grow) * N + gcol] = v;
                }
            }
        }
    }
}

// ---------------------------------------------------------------------------
// Fused out_proj + residual + LayerNorm1 + gate (round-10 verified).
// ---------------------------------------------------------------------------
__global__ __launch_bounds__(256) void oproj_ln(
    const ushort_t* __restrict__ Actx, const ushort_t* __restrict__ Wb,
    const float* __restrict__ bias, float* __restrict__ h,
    ushort_t* __restrict__ hb,
    const float* __restrict__ g, const float* __restrict__ b,
    const float* __restrict__ gw, const float* __restrict__ gb,
    int* __restrict__ top_idx, float* __restrict__ top_w)
{
    __shared__ ushort_t As[16 * 64];
    __shared__ ushort_t Bs[256 * 64];
    __shared__ float lsum[16][4], lsq[16][4];
    __shared__ float gred[16][NE][4];
    const int m0 = blockIdx.x * 16;
    const int tid = threadIdx.x;
    const int lane = tid & 63, wave = tid >> 6;
    const int r8 = lane >> 3, p = lane & 7;
    const int kswz = ((p ^ r8) << 3);
    const int quad = lane >> 4, fr = lane & 15;
    const int wn = wave * 64;
    floatx4 acc[4];
#pragma unroll
    for (int n = 0; n < 4; n++) acc[n] = (floatx4){0.f, 0.f, 0.f, 0.f};

    for (int k0 = 0; k0 < 256; k0 += 64) {
        __syncthreads();
        if (wave < 2)
            GLD16(Actx + (size_t)(m0 + wave * 8 + r8) * 256 + k0 + kswz,
                  &As[(wave * 8) * 64]);
#pragma unroll
        for (int c = 0; c < 8; c++)
            GLD16(Wb + (size_t)(wn + c * 8 + r8) * 256 + k0 + kswz,
                  &Bs[(wn + c * 8) * 64]);
        __syncthreads();
#pragma unroll
        for (int ks = 0; ks < 2; ks++) {
            const int sw = (((ks * 4 + quad) ^ (fr & 7)) << 3);
            short8 fa = *(const short8*)&As[fr * 64 + sw];
#pragma unroll
            for (int n = 0; n < 4; n++) {
                short8 fb = *(const short8*)&Bs[(wn + n * 16 + fr) * 64 + sw];
                acc[n] = __builtin_amdgcn_mfma_f32_16x16x32_bf16(fa, fb, acc[n], 0, 0, 0);
            }
        }
    }
    const int rbase = quad * 4;
    float val[4][4];
#pragma unroll
    for (int n = 0; n < 4; n++) {
        const int col = wn + n * 16 + fr;
        const float bsv = bias[col];
#pragma unroll
        for (int r = 0; r < 4; r++)
            val[r][n] = acc[n][r] + bsv + h[(size_t)(m0 + rbase + r) * 256 + col];
    }
    float s[4], sq[4];
#pragma unroll
    for (int r = 0; r < 4; r++) {
        s[r]  = val[r][0] + val[r][1] + val[r][2] + val[r][3];
        sq[r] = val[r][0] * val[r][0] + val[r][1] * val[r][1]
              + val[r][2] * val[r][2] + val[r][3] * val[r][3];
    }
#pragma unroll
    for (int ox = 1; ox < 16; ox <<= 1)
#pragma unroll
        for (int r = 0; r < 4; r++) {
            s[r] += __shfl_xor(s[r], ox);
            sq[r] += __shfl_xor(sq[r], ox);
        }
    if (fr == 0)
#pragma unroll
        for (int r = 0; r < 4; r++) { lsum[rbase + r][wave] = s[r]; lsq[rbase + r][wave] = sq[r]; }
    __syncthreads();
    float mu[4], rstd[4];
#pragma unroll
    for (int r = 0; r < 4; r++) {
        const int row = rbase + r;
        const float m = (lsum[row][0] + lsum[row][1] + lsum[row][2] + lsum[row][3]) * (1.f / 256.f);
        float v2 = (lsq[row][0] + lsq[row][1] + lsq[row][2] + lsq[row][3]) * (1.f / 256.f) - m * m;
        mu[r] = m;
        rstd[r] = rsqrtf(fmaxf(v2, 0.f) + 1e-5f);
    }
    float o4[4][4];
#pragma unroll
    for (int n = 0; n < 4; n++) {
        const int col = wn + n * 16 + fr;
        const float gc = g[col], bc = b[col];
#pragma unroll
        for (int r = 0; r < 4; r++) {
            const float o = (val[r][n] - mu[r]) * rstd[r] * gc + bc;
            o4[r][n] = o;
            const size_t idx = (size_t)(m0 + rbase + r) * 256 + col;
            h[idx] = o;
            hb[idx] = bf16r(o);
        }
    }
#pragma unroll
    for (int e = 0; e < NE; e++) {
        float ge[4] = {0.f, 0.f, 0.f, 0.f};
#pragma unroll
        for (int n = 0; n < 4; n++) {
            const float gwv = gw[e * 256 + wn + n * 16 + fr];
#pragma unroll
            for (int r = 0; r < 4; r++) ge[r] += o4[r][n] * gwv;
        }
#pragma unroll
        for (int ox = 1; ox < 16; ox <<= 1)
#pragma unroll
            for (int r = 0; r < 4; r++) ge[r] += __shfl_xor(ge[r], ox);
        if (fr == 0)
#pragma unroll
            for (int r = 0; r < 4; r++) gred[rbase + r][e][wave] = ge[r];
    }
    __syncthreads();
    if (tid < 16) {
        const int row = tid;
        float lg[NE];
        float best = -1e30f; int bi = 0;
#pragma unroll
        for (int e = 0; e < NE; e++) {
            lg[e] = gred[row][e][0] + gred[row][e][1] + gred[row][e][2] + gred[row][e][3] + gb[e];
            if (lg[e] > best) { best = lg[e]; bi = e; }
        }
        float ssum = 0.f;
#pragma unroll
        for (int e = 0; e < NE; e++) ssum += __expf(lg[e] - best);
        top_idx[m0 + row] = bi;
        top_w[m0 + row] = 1.f / ssum;
    }
}

// ---------------------------------------------------------------------------
// Fused MoE fc2 + scale + residual + LN2 — 64-row tiles (4x staging intensity
// vs round-10's 16-row version: B-tile staged by 16 blocks/expert not 64).
// Block = 64 expert-rows x 256 cols; wave w = 64x64 col strip (4x4 frags).
// ---------------------------------------------------------------------------
__global__ __launch_bounds__(256) void fc2_ln64(
    const ushort_t* __restrict__ ehb, const ushort_t* __restrict__ Wb,
    const float* __restrict__ b2, const int* __restrict__ counts,
    const int* __restrict__ perm, const float* __restrict__ topw,
    float* __restrict__ h, ushort_t* __restrict__ hb,
    const float* __restrict__ g, const float* __restrict__ b)
{
    __shared__ ushort_t As[64 * 64];     // 8 KB
    __shared__ ushort_t Bs[256 * 64];    // 32 KB
    __shared__ float lsum[64][4], lsq[64][4];   // 2 KB
    const int e = blockIdx.y;
    const int cnt = counts[e * CSTRIDE];
    const int m0 = blockIdx.x * 64;
    if (m0 >= cnt) return;
    int off = 0;
    for (int i = 0; i < e; i++) off += counts[i * CSTRIDE];
    const ushort_t* Wp = Wb + (size_t)e * 256 * 1024;
    const float* bp = b2 + e * 256;
    const int tid = threadIdx.x;
    const int lane = tid & 63, wave = tid >> 6;
    const int r8 = lane >> 3, p = lane & 7;
    const int kswz = ((p ^ r8) << 3);
    const int quad = lane >> 4, fr = lane & 15;
    const int wn = wave * 64;
    // A staging: wave stages rows wave*16 + c*8 (c=0,1); B: its own col strip.
    size_t asrc[2];
#pragma unroll
    for (int c = 0; c < 2; c++) {
        const int gr = m0 + wave * 16 + c * 8 + r8;
        asrc[c] = (size_t)(off + ((gr < cnt) ? gr : m0));
    }
    floatx4 acc[4][4];
#pragma unroll
    for (int m = 0; m < 4; m++)
#pragma unroll
        for (int n = 0; n < 4; n++) acc[m][n] = (floatx4){0.f, 0.f, 0.f, 0.f};

    for (int k0 = 0; k0 < 1024; k0 += 64) {
        __syncthreads();
#pragma unroll
        for (int c = 0; c < 2; c++)
            GLD16(ehb + asrc[c] * 1024 + k0 + kswz, &As[(wave * 16 + c * 8) * 64]);
#pragma unroll
        for (int c = 0; c < 8; c++)
            GLD16(Wp + (size_t)(wn + c * 8 + r8) * 1024 + k0 + kswz,
                  &Bs[(wn + c * 8) * 64]);
        __syncthreads();
#pragma unroll
        for (int ks = 0; ks < 2; ks++) {
            const int sw = (((ks * 4 + quad) ^ (fr & 7)) << 3);
            short8 fa[4], fb[4];
#pragma unroll
            for (int m = 0; m < 4; m++) fa[m] = *(const short8*)&As[(m * 16 + fr) * 64 + sw];
#pragma unroll
            for (int n = 0; n < 4; n++) fb[n] = *(const short8*)&Bs[(wn + n * 16 + fr) * 64 + sw];
#pragma unroll
            for (int m = 0; m < 4; m++)
#pragma unroll
                for (int n = 0; n < 4; n++)
                    acc[m][n] = __builtin_amdgcn_mfma_f32_16x16x32_bf16(fa[m], fb[n], acc[m][n], 0, 0, 0);
        }
    }
    // ---- epilogue phase 1: bias + scale + residual in place, row partials --
    float gc[4], bc[4], b2c[4];
#pragma unroll
    for (int n = 0; n < 4; n++) {
        const int col = wn + n * 16 + fr;
        gc[n] = g[col]; bc[n] = b[col]; b2c[n] = bp[col];
    }
#pragma unroll
    for (int m = 0; m < 4; m++) {
#pragma unroll
        for (int r = 0; r < 4; r++) {
            const int row = m * 16 + quad * 4 + r;
            const bool v = (m0 + row) < cnt;
            const int tok = perm[off + (v ? (m0 + row) : 0)];
            const float tw = topw[tok];
            float s = 0.f, sq = 0.f;
#pragma unroll
            for (int n = 0; n < 4; n++) {
                const int col = wn + n * 16 + fr;
                float vv = v ? (acc[m][n][r] + b2c[n]) * tw + h[(size_t)tok * 256 + col] : 0.f;
                acc[m][n][r] = vv;
                s += vv; sq += vv * vv;
            }
            for (int ox = 1; ox < 16; ox <<= 1) {
                s += __shfl_xor(s, ox);
                sq += __shfl_xor(sq, ox);
            }
            if (fr == 0) { lsum[row][wave] = s; lsq[row][wave] = sq; }
        }
    }
    __syncthreads();
    // ---- epilogue phase 2: LN + scatter write ----
#pragma unroll
    for (int m = 0; m < 4; m++) {
#pragma unroll
        for (int r = 0; r < 4; r++) {
            const int row = m * 16 + quad * 4 + r;
            if (m0 + row >= cnt) continue;
            const int tok = perm[off + m0 + row];
            const float mu = (lsum[row][0] + lsum[row][1] + lsum[row][2] + lsum[row][3]) * (1.f / 256.f);
            float v2 = (lsq[row][0] + lsq[row][1] + lsq[row][2] + lsq[row][3]) * (1.f / 256.f) - mu * mu;
            const float rstd = rsqrtf(fmaxf(v2, 0.f) + 1e-5f);
#pragma unroll
            for (int n = 0; n < 4; n++) {
                const int col = wn + n * 16 + fr;
                const float o = (acc[m][n][r] - mu) * rstd * gc[n] + bc[n];
                const size_t idx = (size_t)tok * 256 + col;
                h[idx] = o;
                hb[idx] = bf16r(o);
            }
        }
    }
}

// ---------------------------------------------------------------------------
// MFMA flash-style attention (verified round 3).
// ---------------------------------------------------------------------------
__global__ __launch_bounds__(256) void attn_kernel(
    const ushort_t* __restrict__ qkvb, const int* __restrict__ pad,
    ushort_t* __restrict__ ctxb)
{
    __shared__ ushort_t Kt[64 * 40];
    __shared__ ushort_t Vt[32 * 72];
    __shared__ ushort_t Ps[64 * 72];
    __shared__ float padf[512];
    const int tid = threadIdx.x;
    const int lane = tid & 63;
    const int wave = tid >> 6;
    const int quad = lane >> 4;
    const int l16  = lane & 15;
    const int bid = blockIdx.x;
    const int qt = bid & 7;
    const int hh = (bid >> 3) & 7;
    const int b = bid >> 6;
    const int q0 = wave * 16;

    padf[tid]       = (float)pad[b * SEQ + tid];
    padf[tid + 256] = (float)pad[b * SEQ + 256 + tid];

    short8 qfrag = *(const short8*)(qkvb +
        (size_t)(b * SEQ + qt * 64 + q0 + l16) * 768 + hh * 32 + quad * 8);

    const int skey = tid >> 2;
    const int schunk = (tid & 3) * 8;

    floatx4 o0 = {0.f,0.f,0.f,0.f}, o1 = {0.f,0.f,0.f,0.f};
    float lsumr[4] = {0.f, 0.f, 0.f, 0.f};
    const float scale = 0.17677669529663687f;

    for (int t = 0; t < 8; t++) {
        const int kbase = b * SEQ + t * 64;
        __syncthreads();
        uint4 kv = *(const uint4*)(qkvb + (size_t)(kbase + skey) * 768 + 256 + hh * 32 + schunk);
        *(uint4*)&Kt[skey * 40 + schunk] = kv;
        uint4 vv = *(const uint4*)(qkvb + (size_t)(kbase + skey) * 768 + 512 + hh * 32 + schunk);
        ushort_t vs[8]; *(uint4*)vs = vv;
#pragma unroll
        for (int j = 0; j < 8; j++) {
            const int d = schunk + j;
            Vt[d * 72 + (skey ^ ((d >> 3) << 3))] = vs[j];
        }
        __syncthreads();
        floatx4 sfr[4];
#pragma unroll
        for (int fn = 0; fn < 4; fn++) {
            short8 kf = *(const short8*)&Kt[(fn * 16 + l16) * 40 + quad * 8];
            sfr[fn] = __builtin_amdgcn_mfma_f32_16x16x32_bf16(
                qfrag, kf, (floatx4){0.f,0.f,0.f,0.f}, 0, 0, 0);
        }
#pragma unroll
        for (int fn = 0; fn < 4; fn++) {
            const int keyl = fn * 16 + l16;
            const float pv = padf[t * 64 + keyl];
#pragma unroll
            for (int r = 0; r < 4; r++) {
                float pr = (pv != 0.f) ? 0.f : __expf(sfr[fn][r] * scale);
                ushort_t pb = bf16r(pr);
                lsumr[r] += __uint_as_float(((unsigned)pb) << 16);
                Ps[(q0 + quad * 4 + r) * 72 + keyl] = pb;
            }
        }
#pragma unroll
        for (int kc = 0; kc < 2; kc++) {
            short8 pf = *(const short8*)&Ps[(q0 + l16) * 72 + kc * 32 + quad * 8];
            {
                const int d = l16;
                short8 vf = *(const short8*)&Vt[d * 72 + ((kc * 32 + quad * 8) ^ ((d >> 3) << 3))];
                o0 = __builtin_amdgcn_mfma_f32_16x16x32_bf16(pf, vf, o0, 0, 0, 0);
            }
            {
                const int d = 16 + l16;
                short8 vf = *(const short8*)&Vt[d * 72 + ((kc * 32 + quad * 8) ^ ((d >> 3) << 3))];
                o1 = __builtin_amdgcn_mfma_f32_16x16x32_bf16(pf, vf, o1, 0, 0, 0);
            }
        }
    }
#pragma unroll
    for (int r = 0; r < 4; r++) {
        float v = lsumr[r];
        v += __shfl_xor(v, 1); v += __shfl_xor(v, 2);
        v += __shfl_xor(v, 4); v += __shfl_xor(v, 8);
        lsumr[r] = 1.f / v;
    }
    const int nq = b * SEQ + qt * 64 + q0 + quad * 4;
#pragma unroll
    for (int r = 0; r < 4; r++) {
        ushort_t* outp = ctxb + (size_t)(nq + r) * 256 + hh * 32;
        outp[l16]      = bf16r(o0[r] * lsumr[r]);
        outp[16 + l16] = bf16r(o1[r] * lsumr[r]);
    }
}

// ---------------------------------------------------------------------------
__global__ __launch_bounds__(256) void bucket_kernel(
    const int* __restrict__ top_idx, int* __restrict__ pos,
    int* __restrict__ counts)
{
    __shared__ int hist[NE];
    __shared__ int base[NE];
    __shared__ int lpos[256];
    const int n = blockIdx.x * 256 + threadIdx.x;
    if (threadIdx.x < NE) hist[threadIdx.x] = 0;
    __syncthreads();
    const int e = top_idx[n];
    lpos[threadIdx.x] = atomicAdd(&hist[e], 1);
    __syncthreads();
    if (threadIdx.x < NE)
        base[threadIdx.x] = atomicAdd(&counts[threadIdx.x * CSTRIDE], hist[threadIdx.x]);
    __syncthreads();
    pos[n] = base[e] + lpos[threadIdx.x];
}

__global__ __launch_bounds__(256) void scatter_perm(
    const int* __restrict__ top_idx, const int* __restrict__ pos,
    const int* __restrict__ counts, int* __restrict__ perm)
{
    __shared__ int offs_s[NE];
    if (threadIdx.x < NE) {
        int a = 0;
        for (int i = 0; i < (int)threadIdx.x; i++) a += counts[i * CSTRIDE];
        offs_s[threadIdx.x] = a;
    }
    __syncthreads();
    const int n = blockIdx.x * 256 + threadIdx.x;
    if (n < NTOK) perm[offs_s[top_idx[n]] + pos[n]] = n;
}

// ---------------------------------------------------------------------------
__global__ __launch_bounds__(256) void pool1(
    const float* __restrict__ h, const int* __restrict__ pad,
    float* __restrict__ pooled, float* __restrict__ cntb)
{
    const int b = blockIdx.x, c = blockIdx.y, d = threadIdx.x;
    float s = 0.0f; int cnt = 0;
    for (int i = 0; i < 32; i++) {
        const int idx = b * SEQ + c * 32 + i;
        if (!pad[idx]) { s += h[(size_t)idx * D_MODEL + d]; cnt++; }
    }
    atomicAdd(&pooled[b * D_MODEL + d], s);
    if (d == 0) atomicAdd(&cntb[b], (float)cnt);
}

__global__ __launch_bounds__(128) void cls_kernel(
    const float* __restrict__ pooled, const float* __restrict__ cntb,
    const float* __restrict__ fc1w, const float* __restrict__ fc1b,
    const float* __restrict__ fc2w, const float* __restrict__ fc2b,
    float* __restrict__ out)
{
    __shared__ float zs[128];
    const int b = blockIdx.x;
    const int j = threadIdx.x;
    const float invc = 1.0f / fmaxf(cntb[b], 1.0f);
    float s = 0.0f;
    for (int d = 0; d < D_MODEL; d++) s += pooled[b * D_MODEL + d] * fc1w[j * D_MODEL + d];
    zs[j] = fmaxf(s * invc + fc1b[j], 0.0f);
    __syncthreads();
    if (j < 2) {
        float o = fc2b[j];
        for (int i = 0; i < 128; i++) o += zs[i] * fc2w[j * 128 + i];
        out[b * 2 + j] = o;
    }
}

// ---------------------------------------------------------------------------
extern "C" void kernel_launch(void* const* d_in, const int* in_sizes, int n_in,
                              void* d_out, int out_size, void* d_ws, size_t ws_size,
                              hipStream_t stream)
{
    const int*   x          = (const int*)d_in[0];
    const float* emb        = (const float*)d_in[1];
    const float* in_proj_w  = (const float*)d_in[2];
    const float* in_proj_b  = (const float*)d_in[3];
    const float* out_proj_w = (const float*)d_in[4];
    const float* out_proj_b = (const float*)d_in[5];
    const float* ln1_g      = (const float*)d_in[6];
    const float* ln1_b      = (const float*)d_in[7];
    const float* ln2_g      = (const float*)d_in[8];
    const float* ln2_b      = (const float*)d_in[9];
    const float* gate_w     = (const float*)d_in[10];
    const float* gate_b     = (const float*)d_in[11];
    const float* w1         = (const float*)d_in[12];
    const float* b1         = (const float*)d_in[13];
    const float* w2         = (const float*)d_in[14];
    const float* b2         = (const float*)d_in[15];
    const float* fc1_w      = (const float*)d_in[16];
    const float* fc1_b      = (const float*)d_in[17];
    const float* fc2_w      = (const float*)d_in[18];
    const float* fc2_b      = (const float*)d_in[19];
    float* out = (float*)d_out;

    float* ws = (float*)d_ws;
    float*    h      = ws;                          // 2,097,152
    ushort_t* qkvb   = (ushort_t*)(ws + 4194304);   // 8192*768 bf16
    ushort_t* ctxb   = (ushort_t*)(ws + 7340032);   // 8192*256 bf16
    ushort_t* ehb    = (ushort_t*)(ws + 4194304);   // aliases qkvb+ctxb
    ushort_t* hb     = (ushort_t*)(ws + 8388608);   // 8192*256 bf16
    float*    top_w  = ws + 9437184;                // 8192
    float*    pooled = ws + 9445376;
    float*    cntb   = ws + 9449472;
    int*      counts = (int*)(ws + 9449488);        // 2 * NE * CSTRIDE
    int* ipart   = (int*)(ws + 9450000);
    int* pad     = ipart;
    int* top_idx = ipart + 8192;
    int* pos     = ipart + 16384;
    int* perm    = ipart + 24576;
    ushort_t* wball = (ushort_t*)(ws + 9482768);

    wconv_all<<<8704, 256, 0, stream>>>(in_proj_w, out_proj_w, w1, w2, wball);
    embed_kernel<<<NTOK, 256, 0, stream>>>(x, emb, h, hb, pad);
    hipMemsetAsync(pooled, 0, (4096 + 16 + 2 * NE * CSTRIDE) * sizeof(float), stream);

    for (int l = 0; l < 2; l++) {
        const ushort_t* inb_l  = wball + (size_t)l * 196608;
        const ushort_t* outb_l = wball + 393216 + (size_t)l * 65536;
        const ushort_t* w1b_l  = wball + 524288 + (size_t)l * 2097152;
        const ushort_t* w2b_l  = wball + 4718592 + (size_t)l * 2097152;
        int* counts_l = counts + l * NE * CSTRIDE;

        // --- qkv projection ---
        gemm_gl64<<<dim3(768 / 64, NTOK / 64, 1), 256, 0, stream>>>(
            hb, inb_l, in_proj_b + l * 768, qkvb, NTOK, 768, 256,
            nullptr, nullptr, nullptr, GF_OUTBF16);
        // --- attention ---
        attn_kernel<<<NB * NH * (SEQ / 64), 256, 0, stream>>>(qkvb, pad, ctxb);
        // --- out_proj + residual + LN1 + gate (fused) ---
        oproj_ln<<<NTOK / 16, 256, 0, stream>>>(
            ctxb, outb_l, out_proj_b + l * 256, h, hb,
            ln1_g + l * 256, ln1_b + l * 256,
            gate_w + l * NE * 256, gate_b + l * NE, top_idx, top_w);
        // --- routing ---
        bucket_kernel<<<NTOK / 256, 256, 0, stream>>>(top_idx, pos, counts_l);
        scatter_perm<<<NTOK / 256, 256, 0, stream>>>(top_idx, pos, counts_l, perm);
        // --- MoE fc1 (routed expert only) ---
        gemm_gl64<<<dim3(EHID / 64, NTOK / 64, NE), 256, 0, stream>>>(
            hb, w1b_l, b1 + l * NE * EHID, ehb, 0, EHID, 256,
            counts_l, perm, nullptr, GF_GATHER | GF_RELU | GF_OUTBF16);
        // --- MoE fc2 + scale + residual + LN2 (fused, 64-row tiles) ---
        fc2_ln64<<<dim3(NTOK / 64, NE), 256, 0, stream>>>(
            ehb, w2b_l, b2 + l * NE * 256, counts_l, perm, top_w,
            h, hb, ln2_g + l * 256, ln2_b + l * 256);
    }

    pool1<<<dim3(NB, 16), 256, 0, stream>>>(h, pad, pooled, cntb);
    cls_kernel<<<NB, 128, 0, stream>>>(pooled, cntb, fc1_w, fc1_b, fc2_w, fc2_b, out);
}